// Round 1
// baseline (396.194 us; speedup 1.0000x reference)
//
#include <hip/hip_runtime.h>

typedef unsigned short ushort_t;
typedef __attribute__((ext_vector_type(8))) __bf16 bf16x8;
typedef __attribute__((ext_vector_type(4))) float f32x4;

__device__ __forceinline__ f32x4 mfma16(bf16x8 a, bf16x8 b, f32x4 c) {
  return __builtin_amdgcn_mfma_f32_16x16x32_bf16(a, b, c, 0, 0, 0);
}

__device__ __forceinline__ ushort_t f2bf(float f) {
  unsigned int x = __float_as_uint(f);
  unsigned int r = (x + 0x7fffu + ((x >> 16) & 1u)) >> 16;
  return (ushort_t)r;
}

// ---------------- workspace layout (bytes) ----------------
static constexpr size_t SZ_XN   = 4096ull * 512 * 2;      // bf16 [4096][512]
static constexpr size_t SZ_W    = 512ull * 512 * 2;       // bf16 [512][512]
static constexpr size_t OFS_XN   = 0;
static constexpr size_t OFS_YNK  = OFS_XN + SZ_XN;
static constexpr size_t OFS_YNV  = OFS_YNK + SZ_XN;
static constexpr size_t OFS_WQ12 = OFS_YNV + SZ_XN;                // bf16 [1024][512]
static constexpr size_t OFS_WK1  = OFS_WQ12 + 2 * SZ_W;
static constexpr size_t OFS_WV   = OFS_WK1 + SZ_W;
static constexpr size_t OFS_WP1  = OFS_WV + SZ_W;
static constexpr size_t OFS_QB12 = OFS_WP1 + SZ_W;                 // f32 [1024]
static constexpr size_t OFS_FLAG = OFS_QB12 + 4096;
static constexpr size_t OFS_X12  = OFS_FLAG + 256;                 // f32 [4096][1024]
static constexpr size_t OFS_Y1   = OFS_X12 + 4096ull * 1024 * 4;   // f32 [4096][512]
static constexpr size_t OFS_VV   = OFS_Y1 + 4096ull * 512 * 4;     // f32 [4096][512]
static constexpr size_t OFS_Q    = OFS_VV + 4096ull * 512 * 4;     // bf16 [16][2048][256]
static constexpr size_t OFS_K    = OFS_Q + 16ull * 2048 * 256 * 2; // bf16 [16][2048][256]
static constexpr size_t OFS_VT   = OFS_K + 16ull * 2048 * 256 * 2; // bf16 [16][80][2048]
static constexpr size_t OFS_O1   = OFS_VT + 16ull * 80 * 2048 * 2; // bf16 [4096][512]
static constexpr size_t OFS_O2   = OFS_O1 + 4096ull * 512 * 2;     // f32 [4096][24]

// ---------------- weight convert + flag init ----------------
__global__ void k_convert(const float* __restrict__ qW1, const float* __restrict__ qW2,
                          const float* __restrict__ kW1, const float* __restrict__ vW,
                          const float* __restrict__ p1W,
                          const float* __restrict__ qb1, const float* __restrict__ qb2,
                          ushort_t* wq12, ushort_t* wk1, ushort_t* wv, ushort_t* wp1,
                          float* qb12, int* flag) {
  int seg = blockIdx.y;
  int idx = blockIdx.x * 256 + threadIdx.x;  // < 262144
  switch (seg) {
    case 0: wq12[idx] = f2bf(qW1[idx]);
            if (idx < 512) qb12[idx] = qb1[idx];
            if (idx == 0) *flag = 1;
            break;
    case 1: wq12[262144 + idx] = f2bf(qW2[idx]);
            if (idx < 512) qb12[512 + idx] = qb2[idx];
            break;
    case 2: wk1[idx] = f2bf(kW1[idx]); break;
    case 3: wv[idx]  = f2bf(vW[idx]);  break;
    case 4: wp1[idx] = f2bf(p1W[idx]); break;
  }
}

// ---------------- mask == all-ones check ----------------
__global__ void k_maskchk(const float4* __restrict__ mask, int* flag, int n4) {
  int i = blockIdx.x * blockDim.x + threadIdx.x;
  bool bad = false;
  for (; i < n4; i += gridDim.x * blockDim.x) {
    float4 v = mask[i];
    bad |= (v.x != 1.f) | (v.y != 1.f) | (v.z != 1.f) | (v.w != 1.f);
  }
  if (bad) atomicAnd(flag, 0);
}

// ---------------- LayerNorm (single / dual affine) ----------------
__global__ __launch_bounds__(256) void k_ln1(const float* __restrict__ x,
                                             const float* __restrict__ g, const float* __restrict__ b,
                                             ushort_t* __restrict__ out) {
  int row = blockIdx.x, tid = threadIdx.x;
  const float* xr = x + (size_t)row * 512;
  float v0 = xr[tid], v1 = xr[tid + 256];
  float s = v0 + v1, q = v0 * v0 + v1 * v1;
  for (int m = 32; m; m >>= 1) { s += __shfl_xor(s, m, 64); q += __shfl_xor(q, m, 64); }
  __shared__ float ls[8];
  int wid = tid >> 6, lane = tid & 63;
  if (lane == 0) { ls[wid] = s; ls[4 + wid] = q; }
  __syncthreads();
  s = ls[0] + ls[1] + ls[2] + ls[3];
  q = ls[4] + ls[5] + ls[6] + ls[7];
  float mean = s * (1.f / 512), var = q * (1.f / 512) - mean * mean;
  float rs = rsqrtf(var + 1e-5f);
  ushort_t* o = out + (size_t)row * 512;
  o[tid]       = f2bf((v0 - mean) * rs * g[tid] + b[tid]);
  o[tid + 256] = f2bf((v1 - mean) * rs * g[tid + 256] + b[tid + 256]);
}

__global__ __launch_bounds__(256) void k_ln2(const float* __restrict__ y,
                                             const float* __restrict__ g1, const float* __restrict__ b1,
                                             const float* __restrict__ g2, const float* __restrict__ b2,
                                             ushort_t* __restrict__ o1, ushort_t* __restrict__ o2) {
  int row = blockIdx.x, tid = threadIdx.x;
  const float* yr = y + (size_t)row * 512;
  float v0 = yr[tid], v1 = yr[tid + 256];
  float s = v0 + v1, q = v0 * v0 + v1 * v1;
  for (int m = 32; m; m >>= 1) { s += __shfl_xor(s, m, 64); q += __shfl_xor(q, m, 64); }
  __shared__ float ls[8];
  int wid = tid >> 6, lane = tid & 63;
  if (lane == 0) { ls[wid] = s; ls[4 + wid] = q; }
  __syncthreads();
  s = ls[0] + ls[1] + ls[2] + ls[3];
  q = ls[4] + ls[5] + ls[6] + ls[7];
  float mean = s * (1.f / 512), var = q * (1.f / 512) - mean * mean;
  float rs = rsqrtf(var + 1e-5f);
  float t0 = (v0 - mean) * rs, t1 = (v1 - mean) * rs;
  ushort_t* p1 = o1 + (size_t)row * 512;
  ushort_t* p2 = o2 + (size_t)row * 512;
  p1[tid]       = f2bf(t0 * g1[tid] + b1[tid]);
  p1[tid + 256] = f2bf(t1 * g1[tid + 256] + b1[tid + 256]);
  p2[tid]       = f2bf(t0 * g2[tid] + b2[tid]);
  p2[tid + 256] = f2bf(t1 * g2[tid + 256] + b2[tid + 256]);
}

// ---------------- bf16 MFMA GEMM: C[m,j] = sum_k A[m,k]*W[j,k] + bias[j] ----------------
// mode 1: also += p2b[j] + sum_{t<24} o2[m,t]*p2W[j,t]   (final projection)
__global__ __launch_bounds__(256) void k_gemm(const ushort_t* __restrict__ A, const ushort_t* __restrict__ W,
                                              const float* __restrict__ bias, float* __restrict__ Cmat,
                                              int M, int Nn, int K, int mode,
                                              const float* __restrict__ o2, const float* __restrict__ p2W,
                                              const float* __restrict__ p2b) {
  __shared__ __align__(16) ushort_t lA[128 * 40];
  __shared__ __align__(16) ushort_t lB[128 * 40];
  int tid = threadIdx.x;
  int wid = tid >> 6, lane = tid & 63, lg = lane >> 4, lc = lane & 15;
  int m0 = blockIdx.y * 128, n0 = blockIdx.x * 128;
  int wm = wid >> 1, wn = wid & 1;
  f32x4 acc[4][4];
#pragma unroll
  for (int i = 0; i < 4; i++)
#pragma unroll
    for (int j = 0; j < 4; j++) acc[i][j] = (f32x4){0, 0, 0, 0};

  for (int k0 = 0; k0 < K; k0 += 32) {
    __syncthreads();
#pragma unroll
    for (int i = 0; i < 2; i++) {
      int u = tid + i * 256;
      int row = u >> 2, off = u & 3;
      *(int4*)(&lA[row * 40 + off * 8]) = *(const int4*)(A + (size_t)(m0 + row) * K + k0 + off * 8);
      *(int4*)(&lB[row * 40 + off * 8]) = *(const int4*)(W + (size_t)(n0 + row) * K + k0 + off * 8);
    }
    __syncthreads();
    bf16x8 af[4], bf[4];
#pragma unroll
    for (int mt = 0; mt < 4; mt++) af[mt] = *(const bf16x8*)(&lA[(wm * 64 + mt * 16 + lc) * 40 + lg * 8]);
#pragma unroll
    for (int nt = 0; nt < 4; nt++) bf[nt] = *(const bf16x8*)(&lB[(wn * 64 + nt * 16 + lc) * 40 + lg * 8]);
#pragma unroll
    for (int mt = 0; mt < 4; mt++)
#pragma unroll
      for (int nt = 0; nt < 4; nt++) acc[mt][nt] = mfma16(af[mt], bf[nt], acc[mt][nt]);
  }

#pragma unroll
  for (int mt = 0; mt < 4; mt++) {
#pragma unroll
    for (int nt = 0; nt < 4; nt++) {
      int col = n0 + wn * 64 + nt * 16 + lc;
      float bcol = bias[col];
#pragma unroll
      for (int r = 0; r < 4; r++) {
        int row = m0 + wm * 64 + mt * 16 + lg * 4 + r;
        float v = acc[mt][nt][r] + bcol;
        if (mode == 1) {
          const float* o2r = o2 + (size_t)row * 24;
          const float* wr = p2W + (size_t)col * 24;
          float sdot = p2b[col];
#pragma unroll
          for (int j = 0; j < 24; j++) sdot += o2r[j] * wr[j];
          v += sdot;
        }
        Cmat[(size_t)row * Nn + col] = v;
      }
    }
  }
}

// ---------------- q scatter: q[b,h,n,{c,64+c,128+c,192+c}] ----------------
__global__ __launch_bounds__(256) void k_scatter_q(const float* __restrict__ x12, const float* __restrict__ xp,
                                                   const float* __restrict__ pW1, const float* __restrict__ pb1,
                                                   const float* __restrict__ pW2, const float* __restrict__ pb2,
                                                   ushort_t* __restrict__ q) {
  int rown = blockIdx.x;  // b*2048+n
  int b = rown >> 11, n = rown & 2047;
  float p0 = xp[(size_t)rown * 3] * 10.f;
  float p1 = xp[(size_t)rown * 3 + 1] * 10.f;
  float p2v = xp[(size_t)rown * 3 + 2] * 10.f;
  const float* x1r = x12 + (size_t)rown * 1024;
#pragma unroll
  for (int i = 0; i < 2; i++) {
    int e = threadIdx.x + i * 256;
    float a1 = p0 * pW1[e * 3] + p1 * pW1[e * 3 + 1] + p2v * pW1[e * 3 + 2] + pb1[e];
    float a2 = p0 * pW2[e * 3] + p1 * pW2[e * 3 + 1] + p2v * pW2[e * 3 + 2] + pb2[e];
    float c1, s1, c2, s2;
    __sincosf(a1, &s1, &c1);
    __sincosf(a2, &s2, &c2);
    float x1 = x1r[e], x2 = x1r[512 + e];
    int h = e >> 6, c = e & 63;
    ushort_t* qr = q + (((size_t)b * 8 + h) * 2048 + n) * 256;
    qr[c]       = f2bf(x1 * c1);
    qr[64 + c]  = f2bf(x1 * s1);
    qr[128 + c] = f2bf(x2 * c2);
    qr[192 + c] = f2bf(x2 * s2);
  }
}

// ---------------- k scatter (no bias in pos-enc; slots 2/3 are raw cos/sin) ----------------
__global__ __launch_bounds__(256) void k_scatter_k(const float* __restrict__ y1, const float* __restrict__ yp,
                                                   const float* __restrict__ pW1, const float* __restrict__ pW2,
                                                   ushort_t* __restrict__ kk) {
  int rown = blockIdx.x;
  int b = rown >> 11, n = rown & 2047;
  float p0 = yp[(size_t)rown * 3] * 10.f;
  float p1 = yp[(size_t)rown * 3 + 1] * 10.f;
  float p2v = yp[(size_t)rown * 3 + 2] * 10.f;
  const float* y1r = y1 + (size_t)rown * 512;
#pragma unroll
  for (int i = 0; i < 2; i++) {
    int e = threadIdx.x + i * 256;
    float a1 = p0 * pW1[e * 3] + p1 * pW1[e * 3 + 1] + p2v * pW1[e * 3 + 2];
    float a2 = p0 * pW2[e * 3] + p1 * pW2[e * 3 + 1] + p2v * pW2[e * 3 + 2];
    float c1, s1, c2, s2;
    __sincosf(a1, &s1, &c1);
    __sincosf(a2, &s2, &c2);
    float v1 = y1r[e];
    int h = e >> 6, c = e & 63;
    ushort_t* kr = kk + (((size_t)b * 8 + h) * 2048 + n) * 256;
    kr[c]       = f2bf(v1 * c1);
    kr[64 + c]  = f2bf(v1 * s1);
    kr[128 + c] = f2bf(c2);
    kr[192 + c] = f2bf(s2);
  }
}

// ---------------- v transpose: vt[b,h,col,l] = bf16(vv[b,l,h*64+col]) ----------------
__global__ void k_vt(const float* __restrict__ vv, ushort_t* __restrict__ vt) {
  int l0 = blockIdx.x * 64, h = blockIdx.y, b = blockIdx.z;
  __shared__ ushort_t t[64][66];
  int tx = threadIdx.x, ty = threadIdx.y;
#pragma unroll
  for (int i = 0; i < 16; i++) {
    int lr = i * 4 + ty;
    t[lr][tx] = f2bf(vv[((size_t)(b * 2048 + l0 + lr)) * 512 + h * 64 + tx]);
  }
  __syncthreads();
#pragma unroll
  for (int i = 0; i < 16; i++) {
    int col = i * 4 + ty;
    vt[(((size_t)b * 8 + h) * 80 + col) * 2048 + l0 + tx] = t[tx][col];
  }
}

// extra v columns: 64..66 = yp, 67..79 = 0
__global__ void k_vt_extra(const float* __restrict__ yp, ushort_t* __restrict__ vt) {
  int l = blockIdx.x * 256 + threadIdx.x;
  int j = blockIdx.y, bh = blockIdx.z;
  int b = bh >> 3;
  ushort_t v = 0;
  if (j < 3) v = f2bf(yp[((size_t)b * 2048 + l) * 3 + j]);
  vt[((size_t)bh * 80 + 64 + j) * 2048 + l] = v;
}

// ---------------- fused attention ----------------
// grid (N/64, H, B), 256 threads = 4 waves, wave owns 16 rows.
__global__ __launch_bounds__(256, 2) void k_attn(const ushort_t* __restrict__ qbuf,
                                                 const ushort_t* __restrict__ kbuf,
                                                 const ushort_t* __restrict__ vt,
                                                 const float* __restrict__ mask, const int* __restrict__ flag,
                                                 const float* __restrict__ xp,
                                                 float* __restrict__ attn_out, ushort_t* __restrict__ o1,
                                                 float* __restrict__ o2) {
  __shared__ __align__(16) ushort_t kT[64 * 264];
  __shared__ __align__(16) ushort_t vT[80 * 72];
  __shared__ __align__(16) ushort_t aT[4 * 16 * 72];
  int h = blockIdx.y, b = blockIdx.z;
  int bh = b * 8 + h;
  int tid = threadIdx.x, wid = tid >> 6, lane = tid & 63, lg = lane >> 4, lc = lane & 15;
  int n0 = blockIdx.x * 64;
  int wrow = n0 + wid * 16;
  const bool ones = (*flag != 0);

  bf16x8 qf[8];
  {
    const ushort_t* qr = qbuf + ((size_t)bh * 2048 + wrow + lc) * 256 + lg * 8;
#pragma unroll
    for (int ks = 0; ks < 8; ks++) qf[ks] = *(const bf16x8*)(qr + ks * 32);
  }
  float rs0[4] = {0, 0, 0, 0}, rs1[4] = {0, 0, 0, 0};

  // ---- pass 1: row sums of exp(S*scale) (|S*scale| is small -> no max needed) ----
  for (int l0 = 0; l0 < 2048; l0 += 64) {
    __syncthreads();
#pragma unroll
    for (int i = 0; i < 8; i++) {
      int u = tid + i * 256;
      int row = u >> 5, off = u & 31;
      *(int4*)(&kT[row * 264 + off * 8]) =
          *(const int4*)(kbuf + ((size_t)bh * 2048 + l0 + row) * 256 + off * 8);
    }
    __syncthreads();
    f32x4 sacc[4];
#pragma unroll
    for (int nt = 0; nt < 4; nt++) sacc[nt] = (f32x4){0, 0, 0, 0};
#pragma unroll
    for (int ks = 0; ks < 8; ks++)
#pragma unroll
      for (int nt = 0; nt < 4; nt++) {
        bf16x8 kf = *(const bf16x8*)(&kT[(nt * 16 + lc) * 264 + ks * 32 + lg * 8]);
        sacc[nt] = mfma16(qf[ks], kf, sacc[nt]);
      }
    float pr0[4] = {0, 0, 0, 0}, pr1[4] = {0, 0, 0, 0};
#pragma unroll
    for (int nt = 0; nt < 4; nt++)
#pragma unroll
      for (int r = 0; r < 4; r++) {
        float T = __expf(sacc[nt][r] * 0.0625f);
        pr0[r] += T;
        if (!ones) {
          float m = mask[((size_t)b * 2048 + wrow + lg * 4 + r) * 2048 + l0 + nt * 16 + lc];
          pr1[r] += T * m;
        }
      }
#pragma unroll
    for (int r = 0; r < 4; r++) {
#pragma unroll
      for (int s2 = 1; s2 < 16; s2 <<= 1) {
        pr0[r] += __shfl_xor(pr0[r], s2, 64);
        if (!ones) pr1[r] += __shfl_xor(pr1[r], s2, 64);
      }
      rs0[r] += pr0[r];
      rs1[r] += ones ? pr0[r] : pr1[r];
    }
  }
  float inv[4];
#pragma unroll
  for (int r = 0; r < 4; r++) inv[r] = 1.f / (rs1[r] + 1e-8f * rs0[r]);

  // ---- pass 2: recompute S, finalize attn, write, PV (v extended with yp cols) ----
  f32x4 pacc[5];
#pragma unroll
  for (int nt = 0; nt < 5; nt++) pacc[nt] = (f32x4){0, 0, 0, 0};

  for (int l0 = 0; l0 < 2048; l0 += 64) {
    __syncthreads();
#pragma unroll
    for (int i = 0; i < 8; i++) {
      int u = tid + i * 256;
      int row = u >> 5, off = u & 31;
      *(int4*)(&kT[row * 264 + off * 8]) =
          *(const int4*)(kbuf + ((size_t)bh * 2048 + l0 + row) * 256 + off * 8);
    }
#pragma unroll
    for (int i = 0; i < 3; i++) {
      int u = tid + i * 256;
      if (u < 640) {
        int row = u >> 3, off = u & 7;
        *(int4*)(&vT[row * 72 + off * 8]) =
            *(const int4*)(vt + ((size_t)bh * 80 + row) * 2048 + l0 + off * 8);
      }
    }
    __syncthreads();
    f32x4 sacc[4];
#pragma unroll
    for (int nt = 0; nt < 4; nt++) sacc[nt] = (f32x4){0, 0, 0, 0};
#pragma unroll
    for (int ks = 0; ks < 8; ks++)
#pragma unroll
      for (int nt = 0; nt < 4; nt++) {
        bf16x8 kf = *(const bf16x8*)(&kT[(nt * 16 + lc) * 264 + ks * 32 + lg * 8]);
        sacc[nt] = mfma16(qf[ks], kf, sacc[nt]);
      }
#pragma unroll
    for (int nt = 0; nt < 4; nt++)
#pragma unroll
      for (int r = 0; r < 4; r++) {
        float T = __expf(sacc[nt][r] * 0.0625f);
        float m = 1.f;
        if (!ones) m = mask[((size_t)b * 2048 + wrow + lg * 4 + r) * 2048 + l0 + nt * 16 + lc];
        float a = T * m * inv[r];
        attn_out[((size_t)bh * 2048 + wrow + lg * 4 + r) * 2048 + l0 + nt * 16 + lc] = a;
        aT[wid * 1152 + (lg * 4 + r) * 72 + nt * 16 + lc] = f2bf(a);
      }
    asm volatile("s_waitcnt lgkmcnt(0)" ::: "memory");
#pragma unroll
    for (int ks = 0; ks < 2; ks++) {
      bf16x8 af = *(const bf16x8*)(&aT[wid * 1152 + lc * 72 + ks * 32 + lg * 8]);
#pragma unroll
      for (int nt = 0; nt < 5; nt++) {
        bf16x8 vf = *(const bf16x8*)(&vT[(nt * 16 + lc) * 72 + ks * 32 + lg * 8]);
        pacc[nt] = mfma16(af, vf, pacc[nt]);
      }
    }
  }

#pragma unroll
  for (int nt = 0; nt < 4; nt++)
#pragma unroll
    for (int r = 0; r < 4; r++) {
      int n = wrow + lg * 4 + r;
      o1[((size_t)b * 2048 + n) * 512 + h * 64 + nt * 16 + lc] = f2bf(pacc[nt][r]);
    }
  if (lc < 3) {
#pragma unroll
    for (int r = 0; r < 4; r++) {
      int n = wrow + lg * 4 + r;
      o2[((size_t)b * 2048 + n) * 24 + h * 3 + lc] = pacc[4][r] - xp[((size_t)b * 2048 + n) * 3 + lc];
    }
  }
}

// ---------------- launch ----------------
extern "C" void kernel_launch(void* const* d_in, const int* in_sizes, int n_in,
                              void* d_out, int out_size, void* d_ws, size_t ws_size,
                              hipStream_t stream) {
  const float* x    = (const float*)d_in[0];
  const float* xp   = (const float*)d_in[1];
  const float* y    = (const float*)d_in[2];
  const float* yp   = (const float*)d_in[3];
  const float* mask = (const float*)d_in[4];
  const float* pW1  = (const float*)d_in[5];
  const float* pb1  = (const float*)d_in[6];
  const float* pW2  = (const float*)d_in[7];
  const float* pb2  = (const float*)d_in[8];
  const float* qn_g = (const float*)d_in[9];
  const float* qn_b = (const float*)d_in[10];
  const float* qW1  = (const float*)d_in[11];
  const float* qb1  = (const float*)d_in[12];
  const float* qW2  = (const float*)d_in[13];
  const float* qb2  = (const float*)d_in[14];
  const float* kn_g = (const float*)d_in[15];
  const float* kn_b = (const float*)d_in[16];
  const float* kW1  = (const float*)d_in[17];
  const float* kb1  = (const float*)d_in[18];
  const float* vn_g = (const float*)d_in[19];
  const float* vn_b = (const float*)d_in[20];
  const float* vW   = (const float*)d_in[21];
  const float* vb   = (const float*)d_in[22];
  const float* p1W  = (const float*)d_in[23];
  const float* p1b  = (const float*)d_in[24];
  const float* p2W  = (const float*)d_in[25];
  const float* p2b  = (const float*)d_in[26];

  char* ws = (char*)d_ws;
  ushort_t* xn   = (ushort_t*)(ws + OFS_XN);
  ushort_t* ynk  = (ushort_t*)(ws + OFS_YNK);
  ushort_t* ynv  = (ushort_t*)(ws + OFS_YNV);
  ushort_t* wq12 = (ushort_t*)(ws + OFS_WQ12);
  ushort_t* wk1  = (ushort_t*)(ws + OFS_WK1);
  ushort_t* wv   = (ushort_t*)(ws + OFS_WV);
  ushort_t* wp1  = (ushort_t*)(ws + OFS_WP1);
  float*    qb12 = (float*)(ws + OFS_QB12);
  int*      flag = (int*)(ws + OFS_FLAG);
  float*    x12  = (float*)(ws + OFS_X12);
  float*    y1b  = (float*)(ws + OFS_Y1);
  float*    vvb  = (float*)(ws + OFS_VV);
  ushort_t* qb   = (ushort_t*)(ws + OFS_Q);
  ushort_t* kb   = (ushort_t*)(ws + OFS_K);
  ushort_t* vtb  = (ushort_t*)(ws + OFS_VT);
  ushort_t* o1   = (ushort_t*)(ws + OFS_O1);
  float*    o2   = (float*)(ws + OFS_O2);

  float* out0 = (float*)d_out;
  float* attn_out = (float*)d_out + 2097152;  // B*N*E

  k_convert<<<dim3(1024, 5), 256, 0, stream>>>(qW1, qW2, kW1, vW, p1W, qb1, qb2,
                                               wq12, wk1, wv, wp1, qb12, flag);
  k_maskchk<<<2048, 256, 0, stream>>>((const float4*)mask, flag, 2097152);
  k_ln1<<<4096, 256, 0, stream>>>(x, qn_g, qn_b, xn);
  k_ln2<<<4096, 256, 0, stream>>>(y, kn_g, kn_b, vn_g, vn_b, ynk, ynv);
  k_gemm<<<dim3(8, 32), 256, 0, stream>>>(xn, wq12, qb12, x12, 4096, 1024, 512, 0, nullptr, nullptr, nullptr);
  k_gemm<<<dim3(4, 32), 256, 0, stream>>>(ynk, wk1, kb1, y1b, 4096, 512, 512, 0, nullptr, nullptr, nullptr);
  k_gemm<<<dim3(4, 32), 256, 0, stream>>>(ynv, wv, vb, vvb, 4096, 512, 512, 0, nullptr, nullptr, nullptr);
  k_scatter_q<<<4096, 256, 0, stream>>>(x12, xp, pW1, pb1, pW2, pb2, qb);
  k_scatter_k<<<4096, 256, 0, stream>>>(y1b, yp, pW1, pW2, kb);
  k_vt<<<dim3(32, 8, 2), dim3(64, 4), 0, stream>>>(vvb, vtb);
  k_vt_extra<<<dim3(8, 16, 16), 256, 0, stream>>>(yp, vtb);
  k_attn<<<dim3(32, 8, 2), 256, 0, stream>>>(qb, kb, vtb, mask, flag, xp, attn_out, o1, o2);
  k_gemm<<<dim3(4, 32), 256, 0, stream>>>(o1, wp1, p1b, out0, 4096, 512, 512, 1, o2, p2W, p2b);
}

// Round 2
// 362.086 us; speedup vs baseline: 1.0942x; 1.0942x over previous
//
#include <hip/hip_runtime.h>

typedef unsigned short ushort_t;
typedef __attribute__((ext_vector_type(8))) __bf16 bf16x8;
typedef __attribute__((ext_vector_type(4))) float f32x4;

__device__ __forceinline__ f32x4 mfma16(bf16x8 a, bf16x8 b, f32x4 c) {
  return __builtin_amdgcn_mfma_f32_16x16x32_bf16(a, b, c, 0, 0, 0);
}

__device__ __forceinline__ ushort_t f2bf(float f) {
  unsigned int x = __float_as_uint(f);
  unsigned int r = (x + 0x7fffu + ((x >> 16) & 1u)) >> 16;
  return (ushort_t)r;
}

// ---------------- workspace layout (bytes) ----------------
static constexpr size_t SZ_XN   = 4096ull * 512 * 2;      // bf16 [4096][512]
static constexpr size_t SZ_W    = 512ull * 512 * 2;       // bf16 [512][512]
static constexpr size_t OFS_XN   = 0;
static constexpr size_t OFS_YNK  = OFS_XN + SZ_XN;
static constexpr size_t OFS_YNV  = OFS_YNK + SZ_XN;
static constexpr size_t OFS_WQ12 = OFS_YNV + SZ_XN;                // bf16 [1024][512]
static constexpr size_t OFS_WK1  = OFS_WQ12 + 2 * SZ_W;
static constexpr size_t OFS_WV   = OFS_WK1 + SZ_W;
static constexpr size_t OFS_WP1  = OFS_WV + SZ_W;
static constexpr size_t OFS_QB12 = OFS_WP1 + SZ_W;                 // f32 [1024]
static constexpr size_t OFS_FLAG = OFS_QB12 + 4096;
static constexpr size_t OFS_X12  = OFS_FLAG + 256;                 // f32 [4096][1024]
static constexpr size_t OFS_Y1   = OFS_X12 + 4096ull * 1024 * 4;   // f32 [4096][512]
static constexpr size_t OFS_VV   = OFS_Y1 + 4096ull * 512 * 4;     // f32 [4096][512]
static constexpr size_t OFS_Q    = OFS_VV + 4096ull * 512 * 4;     // bf16 [16][2048][256]
static constexpr size_t OFS_K    = OFS_Q + 16ull * 2048 * 256 * 2; // bf16 [16][2048][256]
static constexpr size_t OFS_VT   = OFS_K + 16ull * 2048 * 256 * 2; // bf16 [16][80][2048]
static constexpr size_t OFS_O1   = OFS_VT + 16ull * 80 * 2048 * 2; // bf16 [4096][512]
static constexpr size_t OFS_O2   = OFS_O1 + 4096ull * 512 * 2;     // f32 [4096][24]

// ---------------- weight convert + flag init ----------------
__global__ void k_convert(const float* __restrict__ qW1, const float* __restrict__ qW2,
                          const float* __restrict__ kW1, const float* __restrict__ vW,
                          const float* __restrict__ p1W,
                          const float* __restrict__ qb1, const float* __restrict__ qb2,
                          ushort_t* wq12, ushort_t* wk1, ushort_t* wv, ushort_t* wp1,
                          float* qb12, int* flag) {
  int seg = blockIdx.y;
  int idx = blockIdx.x * 256 + threadIdx.x;  // < 262144
  switch (seg) {
    case 0: wq12[idx] = f2bf(qW1[idx]);
            if (idx < 512) qb12[idx] = qb1[idx];
            if (idx == 0) *flag = 1;
            break;
    case 1: wq12[262144 + idx] = f2bf(qW2[idx]);
            if (idx < 512) qb12[512 + idx] = qb2[idx];
            break;
    case 2: wk1[idx] = f2bf(kW1[idx]); break;
    case 3: wv[idx]  = f2bf(vW[idx]);  break;
    case 4: wp1[idx] = f2bf(p1W[idx]); break;
  }
}

// ---------------- mask == all-ones check ----------------
__global__ void k_maskchk(const float4* __restrict__ mask, int* flag, int n4) {
  int i = blockIdx.x * blockDim.x + threadIdx.x;
  bool bad = false;
  for (; i < n4; i += gridDim.x * blockDim.x) {
    float4 v = mask[i];
    bad |= (v.x != 1.f) | (v.y != 1.f) | (v.z != 1.f) | (v.w != 1.f);
  }
  if (bad) atomicAnd(flag, 0);
}

// ---------------- LayerNorm (single / dual affine) ----------------
__global__ __launch_bounds__(256) void k_ln1(const float* __restrict__ x,
                                             const float* __restrict__ g, const float* __restrict__ b,
                                             ushort_t* __restrict__ out) {
  int row = blockIdx.x, tid = threadIdx.x;
  const float* xr = x + (size_t)row * 512;
  float v0 = xr[tid], v1 = xr[tid + 256];
  float s = v0 + v1, q = v0 * v0 + v1 * v1;
  for (int m = 32; m; m >>= 1) { s += __shfl_xor(s, m, 64); q += __shfl_xor(q, m, 64); }
  __shared__ float ls[8];
  int wid = tid >> 6, lane = tid & 63;
  if (lane == 0) { ls[wid] = s; ls[4 + wid] = q; }
  __syncthreads();
  s = ls[0] + ls[1] + ls[2] + ls[3];
  q = ls[4] + ls[5] + ls[6] + ls[7];
  float mean = s * (1.f / 512), var = q * (1.f / 512) - mean * mean;
  float rs = rsqrtf(var + 1e-5f);
  ushort_t* o = out + (size_t)row * 512;
  o[tid]       = f2bf((v0 - mean) * rs * g[tid] + b[tid]);
  o[tid + 256] = f2bf((v1 - mean) * rs * g[tid + 256] + b[tid + 256]);
}

__global__ __launch_bounds__(256) void k_ln2(const float* __restrict__ y,
                                             const float* __restrict__ g1, const float* __restrict__ b1,
                                             const float* __restrict__ g2, const float* __restrict__ b2,
                                             ushort_t* __restrict__ o1, ushort_t* __restrict__ o2) {
  int row = blockIdx.x, tid = threadIdx.x;
  const float* yr = y + (size_t)row * 512;
  float v0 = yr[tid], v1 = yr[tid + 256];
  float s = v0 + v1, q = v0 * v0 + v1 * v1;
  for (int m = 32; m; m >>= 1) { s += __shfl_xor(s, m, 64); q += __shfl_xor(q, m, 64); }
  __shared__ float ls[8];
  int wid = tid >> 6, lane = tid & 63;
  if (lane == 0) { ls[wid] = s; ls[4 + wid] = q; }
  __syncthreads();
  s = ls[0] + ls[1] + ls[2] + ls[3];
  q = ls[4] + ls[5] + ls[6] + ls[7];
  float mean = s * (1.f / 512), var = q * (1.f / 512) - mean * mean;
  float rs = rsqrtf(var + 1e-5f);
  float t0 = (v0 - mean) * rs, t1 = (v1 - mean) * rs;
  ushort_t* p1 = o1 + (size_t)row * 512;
  ushort_t* p2 = o2 + (size_t)row * 512;
  p1[tid]       = f2bf(t0 * g1[tid] + b1[tid]);
  p1[tid + 256] = f2bf(t1 * g1[tid + 256] + b1[tid + 256]);
  p2[tid]       = f2bf(t0 * g2[tid] + b2[tid]);
  p2[tid + 256] = f2bf(t1 * g2[tid + 256] + b2[tid + 256]);
}

// ---------------- bf16 MFMA GEMM: C[m,j] = sum_k A[m,k]*W[j,k] + bias[j] ----------------
__global__ __launch_bounds__(256) void k_gemm(const ushort_t* __restrict__ A, const ushort_t* __restrict__ W,
                                              const float* __restrict__ bias, float* __restrict__ Cmat,
                                              int M, int Nn, int K, int mode,
                                              const float* __restrict__ o2, const float* __restrict__ p2W,
                                              const float* __restrict__ p2b) {
  __shared__ __align__(16) ushort_t lA[128 * 40];
  __shared__ __align__(16) ushort_t lB[128 * 40];
  int tid = threadIdx.x;
  int wid = tid >> 6, lane = tid & 63, lg = lane >> 4, lc = lane & 15;
  int m0 = blockIdx.y * 128, n0 = blockIdx.x * 128;
  int wm = wid >> 1, wn = wid & 1;
  f32x4 acc[4][4];
#pragma unroll
  for (int i = 0; i < 4; i++)
#pragma unroll
    for (int j = 0; j < 4; j++) acc[i][j] = (f32x4){0, 0, 0, 0};

  for (int k0 = 0; k0 < K; k0 += 32) {
    __syncthreads();
#pragma unroll
    for (int i = 0; i < 2; i++) {
      int u = tid + i * 256;
      int row = u >> 2, off = u & 3;
      *(int4*)(&lA[row * 40 + off * 8]) = *(const int4*)(A + (size_t)(m0 + row) * K + k0 + off * 8);
      *(int4*)(&lB[row * 40 + off * 8]) = *(const int4*)(W + (size_t)(n0 + row) * K + k0 + off * 8);
    }
    __syncthreads();
    bf16x8 af[4], bf[4];
#pragma unroll
    for (int mt = 0; mt < 4; mt++) af[mt] = *(const bf16x8*)(&lA[(wm * 64 + mt * 16 + lc) * 40 + lg * 8]);
#pragma unroll
    for (int nt = 0; nt < 4; nt++) bf[nt] = *(const bf16x8*)(&lB[(wn * 64 + nt * 16 + lc) * 40 + lg * 8]);
#pragma unroll
    for (int mt = 0; mt < 4; mt++)
#pragma unroll
      for (int nt = 0; nt < 4; nt++) acc[mt][nt] = mfma16(af[mt], bf[nt], acc[mt][nt]);
  }

#pragma unroll
  for (int mt = 0; mt < 4; mt++) {
#pragma unroll
    for (int nt = 0; nt < 4; nt++) {
      int col = n0 + wn * 64 + nt * 16 + lc;
      float bcol = bias[col];
#pragma unroll
      for (int r = 0; r < 4; r++) {
        int row = m0 + wm * 64 + mt * 16 + lg * 4 + r;
        float v = acc[mt][nt][r] + bcol;
        if (mode == 1) {
          const float* o2r = o2 + (size_t)row * 24;
          const float* wr = p2W + (size_t)col * 24;
          float sdot = p2b[col];
#pragma unroll
          for (int j = 0; j < 24; j++) sdot += o2r[j] * wr[j];
          v += sdot;
        }
        Cmat[(size_t)row * Nn + col] = v;
      }
    }
  }
}

// ---------------- q scatter ----------------
__global__ __launch_bounds__(256) void k_scatter_q(const float* __restrict__ x12, const float* __restrict__ xp,
                                                   const float* __restrict__ pW1, const float* __restrict__ pb1,
                                                   const float* __restrict__ pW2, const float* __restrict__ pb2,
                                                   ushort_t* __restrict__ q) {
  int rown = blockIdx.x;  // b*2048+n
  int b = rown >> 11, n = rown & 2047;
  float p0 = xp[(size_t)rown * 3] * 10.f;
  float p1 = xp[(size_t)rown * 3 + 1] * 10.f;
  float p2v = xp[(size_t)rown * 3 + 2] * 10.f;
  const float* x1r = x12 + (size_t)rown * 1024;
#pragma unroll
  for (int i = 0; i < 2; i++) {
    int e = threadIdx.x + i * 256;
    float a1 = p0 * pW1[e * 3] + p1 * pW1[e * 3 + 1] + p2v * pW1[e * 3 + 2] + pb1[e];
    float a2 = p0 * pW2[e * 3] + p1 * pW2[e * 3 + 1] + p2v * pW2[e * 3 + 2] + pb2[e];
    float c1, s1, c2, s2;
    __sincosf(a1, &s1, &c1);
    __sincosf(a2, &s2, &c2);
    float x1 = x1r[e], x2 = x1r[512 + e];
    int h = e >> 6, c = e & 63;
    ushort_t* qr = q + (((size_t)b * 8 + h) * 2048 + n) * 256;
    qr[c]       = f2bf(x1 * c1);
    qr[64 + c]  = f2bf(x1 * s1);
    qr[128 + c] = f2bf(x2 * c2);
    qr[192 + c] = f2bf(x2 * s2);
  }
}

// ---------------- k scatter ----------------
__global__ __launch_bounds__(256) void k_scatter_k(const float* __restrict__ y1, const float* __restrict__ yp,
                                                   const float* __restrict__ pW1, const float* __restrict__ pW2,
                                                   ushort_t* __restrict__ kk) {
  int rown = blockIdx.x;
  int b = rown >> 11, n = rown & 2047;
  float p0 = yp[(size_t)rown * 3] * 10.f;
  float p1 = yp[(size_t)rown * 3 + 1] * 10.f;
  float p2v = yp[(size_t)rown * 3 + 2] * 10.f;
  const float* y1r = y1 + (size_t)rown * 512;
#pragma unroll
  for (int i = 0; i < 2; i++) {
    int e = threadIdx.x + i * 256;
    float a1 = p0 * pW1[e * 3] + p1 * pW1[e * 3 + 1] + p2v * pW1[e * 3 + 2];
    float a2 = p0 * pW2[e * 3] + p1 * pW2[e * 3 + 1] + p2v * pW2[e * 3 + 2];
    float c1, s1, c2, s2;
    __sincosf(a1, &s1, &c1);
    __sincosf(a2, &s2, &c2);
    float v1 = y1r[e];
    int h = e >> 6, c = e & 63;
    ushort_t* kr = kk + (((size_t)b * 8 + h) * 2048 + n) * 256;
    kr[c]       = f2bf(v1 * c1);
    kr[64 + c]  = f2bf(v1 * s1);
    kr[128 + c] = f2bf(c2);
    kr[192 + c] = f2bf(s2);
  }
}

// ---------------- v transpose ----------------
__global__ void k_vt(const float* __restrict__ vv, ushort_t* __restrict__ vt) {
  int l0 = blockIdx.x * 64, h = blockIdx.y, b = blockIdx.z;
  __shared__ ushort_t t[64][66];
  int tx = threadIdx.x, ty = threadIdx.y;
#pragma unroll
  for (int i = 0; i < 16; i++) {
    int lr = i * 4 + ty;
    t[lr][tx] = f2bf(vv[((size_t)(b * 2048 + l0 + lr)) * 512 + h * 64 + tx]);
  }
  __syncthreads();
#pragma unroll
  for (int i = 0; i < 16; i++) {
    int col = i * 4 + ty;
    vt[(((size_t)b * 8 + h) * 80 + col) * 2048 + l0 + tx] = t[tx][col];
  }
}

__global__ void k_vt_extra(const float* __restrict__ yp, ushort_t* __restrict__ vt) {
  int l = blockIdx.x * 256 + threadIdx.x;
  int j = blockIdx.y, bh = blockIdx.z;
  int b = bh >> 3;
  ushort_t v = 0;
  if (j < 3) v = f2bf(yp[((size_t)b * 2048 + l) * 3 + j]);
  vt[((size_t)bh * 80 + 64 + j) * 2048 + l] = v;
}

// ---------------- fused attention (rewritten) ----------------
// grid flat 512: bh = blk&15 (XCD-pins each bh's K/V into one XCD L2), rb = blk>>4.
// 256 threads = 4 waves; wave owns 16 q-rows; L-tile = 32, double-buffered K in LDS
// via global_load_lds w/ XOR-swizzle (linear dest + inverse-swizzled source).
__global__ __launch_bounds__(256, 2) void k_attn(const ushort_t* __restrict__ qbuf,
                                                 const ushort_t* __restrict__ kbuf,
                                                 const ushort_t* __restrict__ vt,
                                                 const float* __restrict__ mask,
                                                 const int* __restrict__ flag,
                                                 const float* __restrict__ xp,
                                                 float* __restrict__ attn_out,
                                                 ushort_t* __restrict__ o1,
                                                 float* __restrict__ o2) {
  __shared__ __align__(16) ushort_t kL[2][32 * 256];
  __shared__ __align__(16) ushort_t aT[4][16][40];

  int flat = blockIdx.x;
  int bh = flat & 15, rb = flat >> 4;
  int b = bh >> 3, h = bh & 7;
  int tid = threadIdx.x, wid = tid >> 6, lane = tid & 63, lg = lane >> 4, lc = lane & 15;
  int n0 = rb * 64;
  int wrow = n0 + wid * 16;
  const bool ones = (*flag != 0);

  const ushort_t* Kb = kbuf + (size_t)bh * 2048 * 256;
  const ushort_t* Vb = vt + (size_t)bh * 80 * 2048;

  // Q fragments (16 rows per wave), reused across both passes
  bf16x8 qf[8];
  {
    const ushort_t* qr = qbuf + ((size_t)bh * 2048 + wrow + lc) * 256 + lg * 8;
#pragma unroll
    for (int ks = 0; ks < 8; ks++) qf[ks] = *(const bf16x8*)(qr + ks * 32);
  }

  // staging addresses: 1024 granules (16B) per 32x256 tile, 4 per thread
  int sg_src[4], sg_dst[4];
#pragma unroll
  for (int i = 0; i < 4; i++) {
    int g = wid * 256 + i * 64 + lane;
    int row = g >> 5;
    int gc = (g & 31) ^ (row & 7);       // inverse-swizzled source granule
    sg_src[i] = row * 256 + gc * 8;      // ushort offset in global tile
    sg_dst[i] = (wid * 256 + i * 64) * 8;  // wave-uniform linear LDS dest (ushorts)
  }

#define STAGE(s, t)                                                                     \
  {                                                                                     \
    const ushort_t* tb = Kb + (size_t)(t) * 32 * 256;                                   \
    _Pragma("unroll")                                                                   \
    for (int i = 0; i < 4; i++) {                                                       \
      __builtin_amdgcn_global_load_lds(                                                 \
          (const __attribute__((address_space(1))) void*)(tb + sg_src[i]),              \
          (__attribute__((address_space(3))) void*)(&kL[s][sg_dst[i]]), 16, 0, 0);      \
    }                                                                                   \
  }

  int r3 = (lc & 7);  // row&7 is identical for rows lc and 16+lc

  // ---- pass 1: per-lane partial row sums of exp(S*scale) ----
  float rsE[4] = {0, 0, 0, 0}, rsM[4] = {0, 0, 0, 0};
  STAGE(0, 0);
  asm volatile("s_waitcnt vmcnt(0)" ::: "memory");
  __syncthreads();
  for (int t = 0; t < 64; t++) {
    int s = t & 1;
    if (t < 63) { STAGE(s ^ 1, t + 1); }
    __builtin_amdgcn_sched_barrier(0);
    f32x4 sacc[2];
    sacc[0] = (f32x4){0, 0, 0, 0};
    sacc[1] = (f32x4){0, 0, 0, 0};
#pragma unroll
    for (int ks = 0; ks < 8; ks++) {
      int gb = ((ks * 4 + lg) ^ r3) * 8;
      bf16x8 k0 = *(const bf16x8*)(&kL[s][lc * 256 + gb]);
      bf16x8 k1 = *(const bf16x8*)(&kL[s][(16 + lc) * 256 + gb]);
      sacc[0] = mfma16(qf[ks], k0, sacc[0]);
      sacc[1] = mfma16(qf[ks], k1, sacc[1]);
    }
#pragma unroll
    for (int nt = 0; nt < 2; nt++)
#pragma unroll
      for (int r = 0; r < 4; r++) {
        float T = __expf(sacc[nt][r] * 0.0625f);
        rsE[r] += T;
        if (!ones) {
          float m = mask[((size_t)b * 2048 + wrow + lg * 4 + r) * 2048 + t * 32 + nt * 16 + lc];
          rsM[r] += T * m;
        }
      }
    asm volatile("s_waitcnt vmcnt(0)" ::: "memory");
    __syncthreads();
  }

  // one shuffle-reduce over the 16 lc lanes
  float inv[4];
#pragma unroll
  for (int r = 0; r < 4; r++) {
#pragma unroll
    for (int s2 = 1; s2 < 16; s2 <<= 1) {
      rsE[r] += __shfl_xor(rsE[r], s2, 64);
      if (!ones) rsM[r] += __shfl_xor(rsM[r], s2, 64);
    }
    float denom = (ones ? rsE[r] : rsM[r]) + 1e-8f * rsE[r];
    inv[r] = 1.f / denom;
  }

  // ---- pass 2: recompute S, write normalized attn (nontemporal), PV ----
  f32x4 pacc[5];
#pragma unroll
  for (int nt = 0; nt < 5; nt++) pacc[nt] = (f32x4){0, 0, 0, 0};

  STAGE(0, 0);
  asm volatile("s_waitcnt vmcnt(0)" ::: "memory");
  __syncthreads();
  for (int t = 0; t < 64; t++) {
    int s = t & 1;
    if (t < 63) { STAGE(s ^ 1, t + 1); }
    __builtin_amdgcn_sched_barrier(0);
    int l0 = t * 32;
    f32x4 sacc[2];
    sacc[0] = (f32x4){0, 0, 0, 0};
    sacc[1] = (f32x4){0, 0, 0, 0};
#pragma unroll
    for (int ks = 0; ks < 8; ks++) {
      int gb = ((ks * 4 + lg) ^ r3) * 8;
      bf16x8 k0 = *(const bf16x8*)(&kL[s][lc * 256 + gb]);
      bf16x8 k1 = *(const bf16x8*)(&kL[s][(16 + lc) * 256 + gb]);
      sacc[0] = mfma16(qf[ks], k0, sacc[0]);
      sacc[1] = mfma16(qf[ks], k1, sacc[1]);
    }
#pragma unroll
    for (int nt = 0; nt < 2; nt++)
#pragma unroll
      for (int r = 0; r < 4; r++) {
        float T = __expf(sacc[nt][r] * 0.0625f);
        float m = 1.f;
        if (!ones) m = mask[((size_t)b * 2048 + wrow + lg * 4 + r) * 2048 + l0 + nt * 16 + lc];
        float a = T * m * inv[r];
        __builtin_nontemporal_store(
            a, &attn_out[((size_t)bh * 2048 + wrow + lg * 4 + r) * 2048 + l0 + nt * 16 + lc]);
        aT[wid][lg * 4 + r][nt * 16 + lc] = f2bf(a);
      }
    asm volatile("s_waitcnt lgkmcnt(0)" ::: "memory");
    __builtin_amdgcn_sched_barrier(0);
    bf16x8 af = *(const bf16x8*)(&aT[wid][lc][lg * 8]);
#pragma unroll
    for (int nt = 0; nt < 5; nt++) {
      bf16x8 vf = *(const bf16x8*)(Vb + (size_t)(nt * 16 + lc) * 2048 + l0 + lg * 8);
      pacc[nt] = mfma16(af, vf, pacc[nt]);
    }
    // stage loads issued first this iter retire first; leave the 8 nt-stores in flight
    asm volatile("s_waitcnt vmcnt(8)" ::: "memory");
    __syncthreads();
  }
#undef STAGE

#pragma unroll
  for (int nt = 0; nt < 4; nt++)
#pragma unroll
    for (int r = 0; r < 4; r++) {
      int n = wrow + lg * 4 + r;
      o1[((size_t)b * 2048 + n) * 512 + h * 64 + nt * 16 + lc] = f2bf(pacc[nt][r]);
    }
  if (lc < 3) {
#pragma unroll
    for (int r = 0; r < 4; r++) {
      int n = wrow + lg * 4 + r;
      o2[((size_t)b * 2048 + n) * 24 + h * 3 + lc] = pacc[4][r] - xp[((size_t)b * 2048 + n) * 3 + lc];
    }
  }
}

// ---------------- launch ----------------
extern "C" void kernel_launch(void* const* d_in, const int* in_sizes, int n_in,
                              void* d_out, int out_size, void* d_ws, size_t ws_size,
                              hipStream_t stream) {
  const float* x    = (const float*)d_in[0];
  const float* xp   = (const float*)d_in[1];
  const float* y    = (const float*)d_in[2];
  const float* yp   = (const float*)d_in[3];
  const float* mask = (const float*)d_in[4];
  const float* pW1  = (const float*)d_in[5];
  const float* pb1  = (const float*)d_in[6];
  const float* pW2  = (const float*)d_in[7];
  const float* pb2  = (const float*)d_in[8];
  const float* qn_g = (const float*)d_in[9];
  const float* qn_b = (const float*)d_in[10];
  const float* qW1  = (const float*)d_in[11];
  const float* qb1  = (const float*)d_in[12];
  const float* qW2  = (const float*)d_in[13];
  const float* qb2  = (const float*)d_in[14];
  const float* kn_g = (const float*)d_in[15];
  const float* kn_b = (const float*)d_in[16];
  const float* kW1  = (const float*)d_in[17];
  const float* kb1  = (const float*)d_in[18];
  const float* vn_g = (const float*)d_in[19];
  const float* vn_b = (const float*)d_in[20];
  const float* vW   = (const float*)d_in[21];
  const float* vb   = (const float*)d_in[22];
  const float* p1W  = (const float*)d_in[23];
  const float* p1b  = (const float*)d_in[24];
  const float* p2W  = (const float*)d_in[25];
  const float* p2b  = (const float*)d_in[26];

  char* ws = (char*)d_ws;
  ushort_t* xn   = (ushort_t*)(ws + OFS_XN);
  ushort_t* ynk  = (ushort_t*)(ws + OFS_YNK);
  ushort_t* ynv  = (ushort_t*)(ws + OFS_YNV);
  ushort_t* wq12 = (ushort_t*)(ws + OFS_WQ12);
  ushort_t* wk1  = (ushort_t*)(ws + OFS_WK1);
  ushort_t* wv   = (ushort_t*)(ws + OFS_WV);
  ushort_t* wp1  = (ushort_t*)(ws + OFS_WP1);
  float*    qb12 = (float*)(ws + OFS_QB12);
  int*      flag = (int*)(ws + OFS_FLAG);
  float*    x12  = (float*)(ws + OFS_X12);
  float*    y1b  = (float*)(ws + OFS_Y1);
  float*    vvb  = (float*)(ws + OFS_VV);
  ushort_t* qb   = (ushort_t*)(ws + OFS_Q);
  ushort_t* kb   = (ushort_t*)(ws + OFS_K);
  ushort_t* vtb  = (ushort_t*)(ws + OFS_VT);
  ushort_t* o1   = (ushort_t*)(ws + OFS_O1);
  float*    o2   = (float*)(ws + OFS_O2);

  float* out0 = (float*)d_out;
  float* attn_out = (float*)d_out + 2097152;  // B*N*E

  k_convert<<<dim3(1024, 5), 256, 0, stream>>>(qW1, qW2, kW1, vW, p1W, qb1, qb2,
                                               wq12, wk1, wv, wp1, qb12, flag);
  k_maskchk<<<2048, 256, 0, stream>>>((const float4*)mask, flag, 2097152);
  k_ln1<<<4096, 256, 0, stream>>>(x, qn_g, qn_b, xn);
  k_ln2<<<4096, 256, 0, stream>>>(y, kn_g, kn_b, vn_g, vn_b, ynk, ynv);
  k_gemm<<<dim3(8, 32), 256, 0, stream>>>(xn, wq12, qb12, x12, 4096, 1024, 512, 0, nullptr, nullptr, nullptr);
  k_gemm<<<dim3(4, 32), 256, 0, stream>>>(ynk, wk1, kb1, y1b, 4096, 512, 512, 0, nullptr, nullptr, nullptr);
  k_gemm<<<dim3(4, 32), 256, 0, stream>>>(ynv, wv, vb, vvb, 4096, 512, 512, 0, nullptr, nullptr, nullptr);
  k_scatter_q<<<4096, 256, 0, stream>>>(x12, xp, pW1, pb1, pW2, pb2, qb);
  k_scatter_k<<<4096, 256, 0, stream>>>(y1b, yp, pW1, pW2, kb);
  k_vt<<<dim3(32, 8, 2), dim3(64, 4), 0, stream>>>(vvb, vtb);
  k_vt_extra<<<dim3(8, 16, 16), 256, 0, stream>>>(yp, vtb);
  k_attn<<<dim3(512), 256, 0, stream>>>(qb, kb, vtb, mask, flag, xp, attn_out, o1, o2);
  k_gemm<<<dim3(4, 32), 256, 0, stream>>>(o1, wp1, p1b, out0, 4096, 512, 512, 1, o2, p2W, p2b);
}